// Round 2
// baseline (239.985 us; speedup 1.0000x reference)
//
#include <hip/hip_runtime.h>
#include <hip/hip_bf16.h>

// LowRankBilinearFusion on MI355X (gfx950) — v2 (2 dispatches, pipelined)
//
//  1. proj (fused fp32->bf16 convert):
//       up_f32 = u @ Wu^T   (1024x256, D=1024)  -> fp32 (extra precision, free)
//       vp_bf  = v @ Wv^T   (4096x256, D=2048)  -> bf16
//     64x64 tile, K-chunk 128, double-buffered LDS, reg-staged conversion
//     (loads for chunk t+1 issued before MFMA of chunk t -> latency hidden).
//     LDS rows are 256 B -> XOR swizzle ((row&7)<<4) on write+read (T2).
//     XCD swizzle: 4 col-blocks of one row-panel share an XCD (X slice L2-local).
//  2. bilinear: per (b,m,f-half): o = relu( vp[b] @ (up[b,m] (.) Wp)^T + bp )
//     n128 x f128 tile, K=256 in 32-chunks, double-buffered:
//     GL2LDS vp(t+1) + Wp(t+1) reg loads issued before MFMA(t); pack after.
//     Wp consumed as raw fp32 (convert fused into the scale), up read as fp32.
//     XCD swizzle: the 64 blocks of one b share an XCD (vp[b] L2-local).

typedef __attribute__((ext_vector_type(8))) short short8;
typedef __attribute__((ext_vector_type(4))) float floatx4;
typedef __attribute__((ext_vector_type(4))) unsigned uintx4;

// Branch-free RNE fp32->bf16 (finite inputs).
__device__ __forceinline__ short f2bf(float f) {
    union { float f; unsigned u; } cv; cv.f = f;
    unsigned r = cv.u + 0x7fffu + ((cv.u >> 16) & 1u);
    return (short)(r >> 16);
}
// RNE pack of two fp32 into one dword of two bf16 (lo = x, hi = y).
__device__ __forceinline__ unsigned pack_rne(float x, float y) {
    __hip_bfloat162 h = __float22bfloat162_rn(make_float2(x, y));
    union { __hip_bfloat162 h; unsigned u; } cv; cv.h = h;
    return cv.u;
}

#define GL2LDS(gptr, lptr) __builtin_amdgcn_global_load_lds(                    \
    (const __attribute__((address_space(1))) void*)(gptr),                      \
    (__attribute__((address_space(3))) void*)(lptr), 16, 0, 0)

#define MFMA16(a, b, c) __builtin_amdgcn_mfma_f32_16x16x32_bf16((a), (b), (c), 0, 0, 0)

// ---------------------------------------------------------------------------
// Merged projection GEMM, fp32 inputs (conversion fused into staging).
// Blocks 0..63: u-proj (rows=1024, D=1024) -> up fp32
// Blocks 64..319: v-proj (rows=4096, D=2048) -> vp bf16
// 64x64 tile, 256 threads (2x2 waves of 32x32), K-chunk 128, LDS dbuf 64 KB.
// ---------------------------------------------------------------------------
__global__ __launch_bounds__(256) void proj_kernel(
    const float* __restrict__ u, const float* __restrict__ Wu,
    float* __restrict__ upf,
    const float* __restrict__ v, const float* __restrict__ Wv,
    short* __restrict__ vpb)
{
    __shared__ __align__(16) short Xs[2][64 * 128];
    __shared__ __align__(16) short Wsh[2][64 * 128];

    const int tid  = threadIdx.x;
    const int lane = tid & 63;
    const int wave = tid >> 6;
    const int quad = lane >> 4;
    const int l15  = lane & 15;

    const int bid = blockIdx.x;
    const float *X, *W;
    int D, rb, cb;
    bool is_u;
    if (bid < 64) {
        is_u = true; X = u; W = Wu; D = 1024;
        const int xcd = bid & 7, j = bid >> 3;        // j 0..7
        cb = j & 3; rb = (j >> 2) * 8 + xcd;          // rb 0..15
    } else {
        is_u = false; X = v; W = Wv; D = 2048;
        const int lb = bid - 64;                      // 0..255
        const int xcd = lb & 7, j = lb >> 3;          // j 0..31
        cb = j & 3; rb = (j >> 2) * 8 + xcd;          // rb 0..63
    }
    const int r0 = rb * 64, c0 = cb * 64;
    const int wr = (wave >> 1) * 32;
    const int wc = (wave & 1) * 32;

    // staging: thread -> (row sr, 32-float segment sc)
    const int sr = tid >> 2;                 // 0..63
    const int sc = (tid & 3) * 32;           // 0,32,64,96 (floats == shorts)
    const float* xg = X + (size_t)(r0 + sr) * D + sc;
    const float* wg = W + (size_t)(c0 + sr) * D + sc;
    const int swz   = (sr & 7) << 4;         // T2 XOR swizzle (256 B rows)
    const int rbase = sr * 256 + sc * 2;     // byte offset in tile

    floatx4 acc[2][2] = {};

    float4 x0, x1, x2, x3, x4, x5, x6, x7;
    float4 y0, y1, y2, y3, y4, y5, y6, y7;

#define LDC(koff)                                                               \
    x0 = *(const float4*)(xg + (koff));      x1 = *(const float4*)(xg + (koff) + 4);  \
    x2 = *(const float4*)(xg + (koff) + 8);  x3 = *(const float4*)(xg + (koff) + 12); \
    x4 = *(const float4*)(xg + (koff) + 16); x5 = *(const float4*)(xg + (koff) + 20); \
    x6 = *(const float4*)(xg + (koff) + 24); x7 = *(const float4*)(xg + (koff) + 28); \
    y0 = *(const float4*)(wg + (koff));      y1 = *(const float4*)(wg + (koff) + 4);  \
    y2 = *(const float4*)(wg + (koff) + 8);  y3 = *(const float4*)(wg + (koff) + 12); \
    y4 = *(const float4*)(wg + (koff) + 16); y5 = *(const float4*)(wg + (koff) + 20); \
    y6 = *(const float4*)(wg + (koff) + 24); y7 = *(const float4*)(wg + (koff) + 28);

#define PKC(bufi)                                                               \
    { char* xb = (char*)&Xs[bufi][0]; char* wb = (char*)&Wsh[bufi][0];          \
      uintx4 q;                                                                 \
      q[0] = pack_rne(x0.x, x0.y); q[1] = pack_rne(x0.z, x0.w);                 \
      q[2] = pack_rne(x1.x, x1.y); q[3] = pack_rne(x1.z, x1.w);                 \
      *(uintx4*)(xb + ((rbase +  0) ^ swz)) = q;                                \
      q[0] = pack_rne(x2.x, x2.y); q[1] = pack_rne(x2.z, x2.w);                 \
      q[2] = pack_rne(x3.x, x3.y); q[3] = pack_rne(x3.z, x3.w);                 \
      *(uintx4*)(xb + ((rbase + 16) ^ swz)) = q;                                \
      q[0] = pack_rne(x4.x, x4.y); q[1] = pack_rne(x4.z, x4.w);                 \
      q[2] = pack_rne(x5.x, x5.y); q[3] = pack_rne(x5.z, x5.w);                 \
      *(uintx4*)(xb + ((rbase + 32) ^ swz)) = q;                                \
      q[0] = pack_rne(x6.x, x6.y); q[1] = pack_rne(x6.z, x6.w);                 \
      q[2] = pack_rne(x7.x, x7.y); q[3] = pack_rne(x7.z, x7.w);                 \
      *(uintx4*)(xb + ((rbase + 48) ^ swz)) = q;                                \
      q[0] = pack_rne(y0.x, y0.y); q[1] = pack_rne(y0.z, y0.w);                 \
      q[2] = pack_rne(y1.x, y1.y); q[3] = pack_rne(y1.z, y1.w);                 \
      *(uintx4*)(wb + ((rbase +  0) ^ swz)) = q;                                \
      q[0] = pack_rne(y2.x, y2.y); q[1] = pack_rne(y2.z, y2.w);                 \
      q[2] = pack_rne(y3.x, y3.y); q[3] = pack_rne(y3.z, y3.w);                 \
      *(uintx4*)(wb + ((rbase + 16) ^ swz)) = q;                                \
      q[0] = pack_rne(y4.x, y4.y); q[1] = pack_rne(y4.z, y4.w);                 \
      q[2] = pack_rne(y5.x, y5.y); q[3] = pack_rne(y5.z, y5.w);                 \
      *(uintx4*)(wb + ((rbase + 32) ^ swz)) = q;                                \
      q[0] = pack_rne(y6.x, y6.y); q[1] = pack_rne(y6.z, y6.w);                 \
      q[2] = pack_rne(y7.x, y7.y); q[3] = pack_rne(y7.z, y7.w);                 \
      *(uintx4*)(wb + ((rbase + 48) ^ swz)) = q; }

    // prologue: stage chunk 0
    LDC(0);
    PKC(0);
    __syncthreads();

    const int aswz = (l15 & 7) << 4;
    int cur = 0;
    for (int kc = 0; kc < D; kc += 128) {
        const bool has = (kc + 128) < D;
        if (has) { LDC(kc + 128); }               // in flight across MFMA phase

        const char* xr  = (const char*)&Xs[cur][0];
        const char* wrb = (const char*)&Wsh[cur][0];
#pragma unroll
        for (int ks = 0; ks < 4; ks++) {
            const int co = ks * 64 + quad * 16;
            short8 a0 = *(const short8*)(xr  + (((wr +      l15) * 256 + co) ^ aswz));
            short8 a1 = *(const short8*)(xr  + (((wr + 16 + l15) * 256 + co) ^ aswz));
            short8 b0 = *(const short8*)(wrb + (((wc +      l15) * 256 + co) ^ aswz));
            short8 b1 = *(const short8*)(wrb + (((wc + 16 + l15) * 256 + co) ^ aswz));
            acc[0][0] = MFMA16(a0, b0, acc[0][0]);
            acc[0][1] = MFMA16(a0, b1, acc[0][1]);
            acc[1][0] = MFMA16(a1, b0, acc[1][0]);
            acc[1][1] = MFMA16(a1, b1, acc[1][1]);
        }
        if (has) { PKC(cur ^ 1); }                // waits loads, fills other buf
        __syncthreads();
        cur ^= 1;
    }
#undef LDC
#undef PKC

    // C/D layout: col=lane&15, row=quad*4+reg (verified m89/m91)
    if (is_u) {
#pragma unroll
        for (int tn = 0; tn < 2; tn++)
#pragma unroll
            for (int tf = 0; tf < 2; tf++)
#pragma unroll
                for (int r = 0; r < 4; r++) {
                    const int row = r0 + wr + tn * 16 + quad * 4 + r;
                    const int col = c0 + wc + tf * 16 + l15;
                    upf[(size_t)row * 256 + col] = acc[tn][tf][r];
                }
    } else {
#pragma unroll
        for (int tn = 0; tn < 2; tn++)
#pragma unroll
            for (int tf = 0; tf < 2; tf++)
#pragma unroll
                for (int r = 0; r < 4; r++) {
                    const int row = r0 + wr + tn * 16 + quad * 4 + r;
                    const int col = c0 + wc + tf * 16 + l15;
                    vpb[(size_t)row * 256 + col] = f2bf(acc[tn][tf][r]);
                }
    }
}

// ---------------------------------------------------------------------------
// Bilinear fusion. One block = one (b,m) x one 128-wide f-half.
// n=128 x f=128 tile, 4 waves 2x2, each wave 64x64 (4x4 MFMA tiles).
// K=256 in chunks of 32, double-buffered: vp via GL2LDS, W' = up (.) Wp
// reg-staged from fp32 Wp with RNE pack. Staging for t+1 overlaps MFMA(t).
// ---------------------------------------------------------------------------
__global__ __launch_bounds__(256) void bilinear_kernel(
    const float* __restrict__ up, const short* __restrict__ vp,
    const float* __restrict__ Wp, const float* __restrict__ bp,
    float* __restrict__ out)
{
    __shared__ __align__(16) short vp_s[2][128 * 32];  // linear (GL2LDS dst)
    __shared__ __align__(16) short Ws[2][128 * 32];
    __shared__ float up_s[256];

    const int tid  = threadIdx.x;
    const int lane = tid & 63;
    const int wave = tid >> 6;
    const int quad = lane >> 4;
    const int l15  = lane & 15;

    // XCD-aware decode: all 64 blocks of one b share bid%8 == b%8.
    const int bid = blockIdx.x;
    const int xcd = bid & 7;
    const int grp = bid >> 3;                 // 0..255
    const int s   = grp & 63;                 // 0..63 within b-group
    const int b   = (grp >> 6) * 8 + xcd;     // 0..31
    const int m   = s >> 1;
    const int f_blk = s & 1;
    const int bm  = b * 32 + m;
    const int f0  = f_blk * 128;
    const int wn  = (wave >> 1) * 64;
    const int wf  = (wave & 1) * 64;

    // vp staging: 2 x 16B GL2LDS per thread per chunk
    const int sr  = tid >> 2;                 // 0..63
    const int skg = (tid & 3) * 8;            // 0,8,16,24 (shorts)
    // W' staging: 16 elems per thread per chunk
    const int sn  = tid >> 1;                 // 0..127
    const int skh = (tid & 1) * 16;           // 0 or 16

    up_s[tid] = up[(size_t)bm * 256 + tid];   // fp32 up row

    const short* vg = vp + (size_t)(b * 128 + sr) * 256 + skg;
    const float* wq = Wp + (size_t)(f0 + sn) * 256 + skh;

    // prologue: stage chunk 0
    GL2LDS(vg,            &vp_s[0][sr * 32 + skg]);
    GL2LDS(vg + 64 * 256, &vp_s[0][(64 + sr) * 32 + skg]);
    float4 w0 = *(const float4*)wq;
    float4 w1 = *(const float4*)(wq + 4);
    float4 w2 = *(const float4*)(wq + 8);
    float4 w3 = *(const float4*)(wq + 12);
    __syncthreads();                          // up_s + vp_s[0] visible
    {
        const float* us = &up_s[skh];
        float4 u0 = *(const float4*)us,       u1 = *(const float4*)(us + 4),
               u2 = *(const float4*)(us + 8), u3 = *(const float4*)(us + 12);
        uintx4 o0, o1;
        o0[0] = pack_rne(w0.x * u0.x, w0.y * u0.y);
        o0[1] = pack_rne(w0.z * u0.z, w0.w * u0.w);
        o0[2] = pack_rne(w1.x * u1.x, w1.y * u1.y);
        o0[3] = pack_rne(w1.z * u1.z, w1.w * u1.w);
        o1[0] = pack_rne(w2.x * u2.x, w2.y * u2.y);
        o1[1] = pack_rne(w2.z * u2.z, w2.w * u2.w);
        o1[2] = pack_rne(w3.x * u3.x, w3.y * u3.y);
        o1[3] = pack_rne(w3.z * u3.z, w3.w * u3.w);
        *(uintx4*)&Ws[0][sn * 32 + skh]     = o0;
        *(uintx4*)&Ws[0][sn * 32 + skh + 8] = o1;
    }
    __syncthreads();

    floatx4 acc[4][4] = {};

#pragma unroll
    for (int kc = 0; kc < 256; kc += 32) {
        const int cur = (kc >> 5) & 1;
        const int nxt = cur ^ 1;
        const bool has = kc < 224;
        float4 v0, v1, v2, v3;
        if (has) {   // stage chunk t+1 while computing t
            const short* g = vg + kc + 32;
            GL2LDS(g,            &vp_s[nxt][sr * 32 + skg]);
            GL2LDS(g + 64 * 256, &vp_s[nxt][(64 + sr) * 32 + skg]);
            const float* wqn = wq + kc + 32;
            v0 = *(const float4*)wqn;       v1 = *(const float4*)(wqn + 4);
            v2 = *(const float4*)(wqn + 8); v3 = *(const float4*)(wqn + 12);
        }

        short8 a[4], bb[4];
#pragma unroll
        for (int tt = 0; tt < 4; tt++)
            a[tt] = *(const short8*)&vp_s[cur][(wn + tt * 16 + l15) * 32 + quad * 8];
#pragma unroll
        for (int tt = 0; tt < 4; tt++)
            bb[tt] = *(const short8*)&Ws[cur][(wf + tt * 16 + l15) * 32 + quad * 8];
#pragma unroll
        for (int tn = 0; tn < 4; tn++)
#pragma unroll
            for (int tf = 0; tf < 4; tf++)
                acc[tn][tf] = MFMA16(a[tn], bb[tf], acc[tn][tf]);

        if (has) {   // pack W'(t+1) after MFMA: loads had the whole phase to land
            const float* us = &up_s[kc + 32 + skh];
            float4 u0 = *(const float4*)us,       u1 = *(const float4*)(us + 4),
                   u2 = *(const float4*)(us + 8), u3 = *(const float4*)(us + 12);
            uintx4 o0, o1;
            o0[0] = pack_rne(v0.x * u0.x, v0.y * u0.y);
            o0[1] = pack_rne(v0.z * u0.z, v0.w * u0.w);
            o0[2] = pack_rne(v1.x * u1.x, v1.y * u1.y);
            o0[3] = pack_rne(v1.z * u1.z, v1.w * u1.w);
            o1[0] = pack_rne(v2.x * u2.x, v2.y * u2.y);
            o1[1] = pack_rne(v2.z * u2.z, v2.w * u2.w);
            o1[2] = pack_rne(v3.x * u3.x, v3.y * u3.y);
            o1[3] = pack_rne(v3.z * u3.z, v3.w * u3.w);
            *(uintx4*)&Ws[nxt][sn * 32 + skh]     = o0;
            *(uintx4*)&Ws[nxt][sn * 32 + skh + 8] = o1;
        }
        __syncthreads();   // vp_s[nxt] (vmcnt drain) + Ws[nxt] ready
    }

    float bpv[4];
#pragma unroll
    for (int tf = 0; tf < 4; tf++) bpv[tf] = bp[f0 + wf + tf * 16 + l15];

    const size_t out_base = (size_t)bm * 128 * 256;
#pragma unroll
    for (int tn = 0; tn < 4; tn++)
#pragma unroll
        for (int r = 0; r < 4; r++) {
            const int n = wn + tn * 16 + quad * 4 + r;
            float* op = out + out_base + (size_t)n * 256 + f0 + wf + l15;
#pragma unroll
            for (int tf = 0; tf < 4; tf++) {
                float val = acc[tn][tf][r] + bpv[tf];
                op[tf * 16] = fmaxf(val, 0.0f);
            }
        }
}

extern "C" void kernel_launch(void* const* d_in, const int* in_sizes, int n_in,
                              void* d_out, int out_size, void* d_ws, size_t ws_size,
                              hipStream_t stream) {
    const float* u  = (const float*)d_in[0];   // (32,32,1024)
    const float* v  = (const float*)d_in[1];   // (32,128,2048)
    const float* Wu = (const float*)d_in[2];   // (256,1024)
    const float* Wv = (const float*)d_in[3];   // (256,2048)
    const float* Wp = (const float*)d_in[4];   // (256,256)
    const float* bp = (const float*)d_in[5];   // (256,)
    float* out = (float*)d_out;                // (32,32,128,256)

    float* up_f  = (float*)d_ws;               // 1024*256 fp32
    short* vp_bf = (short*)(up_f + 262144);    // 4096*256 bf16

    // blocks 0..63: up (16 rblk x 4 cblk); 64..319: vp (64 rblk x 4 cblk)
    proj_kernel<<<dim3(320), dim3(256), 0, stream>>>(
        u, Wu, up_f, v, Wv, vp_bf);
    bilinear_kernel<<<dim3(2048), dim3(256), 0, stream>>>(
        up_f, vp_bf, Wp, bp, out);
}